// Round 6
// baseline (417.989 us; speedup 1.0000x reference)
//
#include <hip/hip_runtime.h>
#include <math.h>

#define NUMPIX 256
#define NUMBIN 367
#define NUMTHETA 360
#define NS 4
#define NT 367
#define NPIX2 (NUMPIX * NUMPIX)          // 65536
#define NRAYS_ALL (NUMTHETA * NUMBIN)    // 132120
#define NANG_SUB (NUMTHETA / NS)         // 90
#define NRAYS_SUB (NANG_SUB * NUMBIN)    // 33030

#define CDET 183.0f
#define CPIX 127.5f
#define TOFF 183.0f                      // (NT-1)/2
#define DEN_EPS 1e-6f
#define EPS_F 2.2204460492503131e-16f    // float64 eps
#define RES2_THRESH 1e-4f                // (0.01)^2
#define INV_DINV (1.0f / 90.0f)          // backproject(ones) == 90 exactly

// quad-interleaved image: element (r,c) = float2(img[r][c], img[r+1][c])
// rows r in [-1,256] stored at +1 (258 rows), cols c in [-1,258] at +1
#define QW 260                           // float2 stride
#define QROWS 258
#define QN2 (QW * QROWS)                 // 67080 float2
#define QNF (QN2 * 2)                    // 134160 floats

#define RES_BLOCKS 1024                  // MODE-2 grid (grid-stride)

typedef float f4q __attribute__((ext_vector_type(4), aligned(8)));
typedef float f2u __attribute__((ext_vector_type(2), aligned(4)));

// ---- workspace layout (in floats) ----
#define OFF_COS   0
#define OFF_SIN   (OFF_COS + NUMTHETA)           // 360
#define OFF_MINV  (OFF_SIN + NUMTHETA)           // 720
#define OFF_FK    (OFF_MINV + NRAYS_ALL)         // 132840
#define OFF_Q     (OFF_FK + NPIX2)               // 198376 (even -> float2 ok)
#define OFF_QT    (OFF_Q + QNF)                  // 332536
#define OFF_DIFF  (OFF_QT + QNF)                 // 466696 (also residual partials)

// generic t-interval clip: keep c0 + rate*tt within (bLo, bHi)
__device__ __forceinline__ void clip_axis2(float c0, float rate,
                                           float bLo, float bHi,
                                           float& lo, float& hi) {
    if (fabsf(rate) > 1e-6f) {
        float inv = 1.0f / rate;
        float a = (bLo - c0) * inv;
        float b = (bHi - c0) * inv;
        lo = fmaxf(lo, fminf(a, b));
        hi = fminf(hi, fmaxf(a, b));
    } else if (c0 <= bLo || c0 >= bHi) {
        lo = 1e9f; hi = -1e9f;
    }
}

__device__ __forceinline__ int ray_chunks(float x0, float y0, float ca, float sa,
                                          int& itlo) {
    float lo = -1e9f, hi = 1e9f;
    clip_axis2(x0, -sa, -2.0f, 257.0f, lo, hi);
    clip_axis2(y0,  ca, -2.0f, 257.0f, lo, hi);
    if (hi < lo) { itlo = 0; return 0; }
    int a = (int)floorf(lo + TOFF) - 1; if (a < 0) a = 0;
    int b = (int)ceilf(hi + TOFF) + 1;  if (b > NT - 1) b = NT - 1;
    itlo = a;
    if (b < a) return 0;
    return (b - a + 64) >> 6;
}

// ---------------- init: trig + fk/fcur + quad images ----------------
__global__ void init_kernel(float* __restrict__ cosA, float* __restrict__ sinA,
                            float* __restrict__ Qf, float* __restrict__ QTf,
                            float* __restrict__ fk, float* __restrict__ fcur,
                            const float* __restrict__ f0) {
    int idx = blockIdx.x * blockDim.x + threadIdx.x;
    if (idx < NUMTHETA) {
        float th = (float)((double)idx * 0.017453292519943295);
        cosA[idx] = (float)cos((double)th);
        sinA[idx] = (float)sin((double)th);
    }
    if (idx < NPIX2) {
        float v = f0[idx];
        fk[idx] = v;
        fcur[idx] = v;
    }
    if (idx < QN2) {
        int qr = idx / QW, qc = idx - qr * QW;
        int r = qr - 1, c = qc - 1;                 // r in [-1,256], c in [-1,258]
        bool cv = ((unsigned)c < 256u);
        bool rv0 = ((unsigned)r < 256u), rv1 = ((unsigned)(r + 1) < 256u);
        float a = (cv && rv0) ? f0[r * NUMPIX + c] : 0.0f;
        float b = (cv && rv1) ? f0[(r + 1) * NUMPIX + c] : 0.0f;
        Qf[idx * 2] = a;  Qf[idx * 2 + 1] = b;
        // transposed image: imgT(r,c) = f0[c][r]
        bool rv = ((unsigned)r < 256u) || true;     // reuse checks below
        float at = (cv && rv0) ? 0.0f : 0.0f;       // placeholder, computed next
        (void)rv; (void)at;
        float ta = (((unsigned)c < 256u) && ((unsigned)r < 256u)) ? f0[c * NUMPIX + r] : 0.0f;
        float tb = (((unsigned)c < 256u) && ((unsigned)(r + 1) < 256u)) ? f0[c * NUMPIX + (r + 1)] : 0.0f;
        QTf[idx * 2] = ta;  QTf[idx * 2 + 1] = tb;
    }
}

// ---------------- Minv: analytic interior count + exact edge samples -----
__global__ __launch_bounds__(256)
void minv_kernel(float* __restrict__ minv,
                 const float* __restrict__ cosA,
                 const float* __restrict__ sinA) {
    const int wid = threadIdx.x >> 6, lane = threadIdx.x & 63;
    int ray = blockIdx.x * 4 + wid;               // grid 33030 -> 132120 exact
    int angle = ray / NUMBIN;
    int bin = ray - angle * NUMBIN;
    float ca = cosA[angle], sa = sinA[angle];
    float s = (float)bin - CDET;
    float x0 = fmaf(s, ca, CPIX);                 // x(tt) = x0 - tt*sa
    float y0 = fmaf(s, sa, CPIX);                 // y(tt) = y0 + tt*ca
    float acc = 0.0f;
    int count = 0;
    float lo = -1e9f, hi = 1e9f;
    clip_axis2(x0, -sa, -2.0f, 257.0f, lo, hi);
    clip_axis2(y0,  ca, -2.0f, 257.0f, lo, hi);
    int e1a = 0, e1b = -1, e2a = 0, e2b = -1;
    if (hi >= lo) {
        int itA = (int)floorf(lo + TOFF) - 1; if (itA < 0) itA = 0;
        int itB = (int)ceilf(hi + TOFF) + 1;  if (itB > NT - 1) itB = NT - 1;
        if (itB >= itA) {
            // strict interior: both coords in (0.05, 254.95) -> weight exactly 1
            float ilo = -1e9f, ihi = 1e9f;
            clip_axis2(x0, -sa, 0.05f, 254.95f, ilo, ihi);
            clip_axis2(y0,  ca, 0.05f, 254.95f, ilo, ihi);
            int jA = 1, jB = 0;
            if (ihi >= ilo) {
                jA = (int)ceilf(ilo + TOFF) + 1;
                jB = (int)floorf(ihi + TOFF) - 1;
                if (jA < itA) jA = itA;
                if (jB > itB) jB = itB;
            }
            if (jB >= jA) {
                count = jB - jA + 1;
                e1a = itA; e1b = jA - 1;
                e2a = jB + 1; e2b = itB;
            } else {
                e1a = itA; e1b = itB;       // no interior: one full edge loop
            }
        }
    }
    #pragma unroll 1
    for (int base = e1a; base <= e1b; base += 64) {
        int t = base + lane;
        float tt = (float)t - TOFF;
        float x = fmaf(-tt, sa, x0);
        float y = fmaf(tt, ca, y0);
        float fx = floorf(x), fy = floorf(y);
        float wx = x - fx, wy = y - fy;
        int c0 = (int)fx, r0 = (int)fy;
        float ux = (((unsigned)c0 < 256u) ? (1.0f - wx) : 0.0f) +
                   (((unsigned)(c0 + 1) < 256u) ? wx : 0.0f);
        float uy = (((unsigned)r0 < 256u) ? (1.0f - wy) : 0.0f) +
                   (((unsigned)(r0 + 1) < 256u) ? wy : 0.0f);
        if (t <= e1b) acc += ux * uy;
    }
    #pragma unroll 1
    for (int base = e2a; base <= e2b; base += 64) {
        int t = base + lane;
        float tt = (float)t - TOFF;
        float x = fmaf(-tt, sa, x0);
        float y = fmaf(tt, ca, y0);
        float fx = floorf(x), fy = floorf(y);
        float wx = x - fx, wy = y - fy;
        int c0 = (int)fx, r0 = (int)fy;
        float ux = (((unsigned)c0 < 256u) ? (1.0f - wx) : 0.0f) +
                   (((unsigned)(c0 + 1) < 256u) ? wx : 0.0f);
        float uy = (((unsigned)r0 < 256u) ? (1.0f - wy) : 0.0f) +
                   (((unsigned)(r0 + 1) < 256u) ? wy : 0.0f);
        if (t <= e2b) acc += ux * uy;
    }
    #pragma unroll
    for (int off = 32; off; off >>= 1) acc += __shfl_down(acc, off);
    if (lane == 0) minv[ray] = fmaxf(acc + (float)count, DEN_EPS);
}

// ---------------- forward projection (quad layout: 1 load = 4 corners) ---
// MODE 1: one ray/wave; diffs[ray] = (sino - FP) / Minv
// MODE 2: grid-stride; out[blockIdx.x] = block partial of sum((FP - sino)^2)
template <int MODE>
__global__ __launch_bounds__(256)
void fp_kernel(const float* __restrict__ Qn,
               const float* __restrict__ Qt,
               const float* __restrict__ sino,
               const float* __restrict__ minv,
               float* __restrict__ out,
               const float* __restrict__ cosA,
               const float* __restrict__ sinA,
               int angleStart, int angleStride, int nRays) {
    const int wid = threadIdx.x >> 6, lane = threadIdx.x & 63;
    float wacc = 0.0f;

    int ray = blockIdx.x * 4 + wid;
    if (MODE == 1 && ray >= nRays) return;
    const int rayStep = RES_BLOCKS * 4;

    for (; ray < nRays; ray += rayStep) {
        int ai = ray / NUMBIN;
        int bin = ray - ai * NUMBIN;
        int angle = angleStart + ai * angleStride;
        float ca = cosA[angle], sa = sinA[angle];
        float s = (float)bin - CDET;
        float x0 = fmaf(s, ca, CPIX);             // x(tt) = x0 - tt*sa
        float y0 = fmaf(s, sa, CPIX);             // y(tt) = y0 + tt*ca
        int itlo, nc = ray_chunks(x0, y0, ca, sa, itlo);

        bool useT = fabsf(ca) > fabsf(sa);        // wave-uniform
        const float* img = (useT ? Qt : Qn) + (QW + 1) * 2;  // origin (r=0,c=0)
        float u0 = useT ? y0 : x0, du = useT ? ca : -sa;   // fast (contiguous)
        float v0 = useT ? x0 : y0, dv = useT ? -sa : ca;   // slow (strided)

        float tt0 = (float)(itlo + lane) - TOFF;
        float u = fmaf(tt0, du, u0);
        float v = fmaf(tt0, dv, v0);
        const float du64 = du * 64.0f, dv64 = dv * 64.0f;

        float acc = 0.0f;
        for (int ic = 0; ic < nc; ic++) {
            float uc = fminf(fmaxf(u, -1.0f), 256.0f);   // into zero guard band
            float vc = fminf(fmaxf(v, -1.0f), 256.0f);
            float fu = floorf(uc), fv = floorf(vc);
            float wu = uc - fu, wv = vc - fv;
            int cu = (int)fu, rv = (int)fv;
            const float* p = img + (rv * QW + cu) * 2;
            f4q q = *(const f4q*)p;   // (v00, v10, v01, v11) in one 16B load
            float top = fmaf(wu, q.z - q.x, q.x);
            float bot = fmaf(wu, q.w - q.y, q.y);
            acc += fmaf(wv, bot - top, top);
            u += du64; v += dv64;
        }
        #pragma unroll
        for (int off = 32; off; off >>= 1) acc += __shfl_down(acc, off);
        if (lane == 0) {
            if (MODE == 1) {
                out[ray] = (sino[angle * NUMBIN + bin] - acc) /
                           minv[angle * NUMBIN + bin];
            } else {
                float d = acc - sino[angle * NUMBIN + bin];
                wacc += d * d;
            }
        }
        if (MODE == 1) break;
    }
    if (MODE == 2) {
        __shared__ float part[4];
        if (lane == 0) part[wid] = wacc;
        __syncthreads();
        if (threadIdx.x == 0)
            out[blockIdx.x] = part[0] + part[1] + part[2] + part[3];
    }
}

// ---------------- backprojection + SART update ----------------
__global__ __launch_bounds__(256)
void bp_update_kernel(float* __restrict__ fk,
                      float* __restrict__ Qf,
                      float* __restrict__ QTf,
                      const float* __restrict__ g,      // diffs [90,367]
                      const float* __restrict__ cosA,
                      const float* __restrict__ sinA,
                      int j, int doClamp) {
    __shared__ float part[4][64];
    const int tx = threadIdx.x & 63;
    const int ty = threadIdx.x >> 6;
    int p = blockIdx.x * 64 + tx;
    int px = p & (NUMPIX - 1), py = p >> 8;
    float X = (float)px - CPIX, Y = (float)py - CPIX;
    float acc = 0.0f;
    for (int i = ty; i < NANG_SUB; i += 4) {
        int angle = j + NS * i;
        float ca = cosA[angle], sa = sinA[angle];
        float sd = fmaf(X, ca, fmaf(Y, sa, CDET));   // always in [2.7, 363.3]
        float f0 = floorf(sd);
        float w = sd - f0;
        int i0 = (int)f0;
        f2u gv = *(const f2u*)(g + i * NUMBIN + i0);
        acc += fmaf(w, gv.y - gv.x, gv.x);
    }
    part[ty][tx] = acc;
    __syncthreads();
    if (ty == 0) {
        float s = part[0][tx] + part[1][tx] + part[2][tx] + part[3][tx];
        float bp = (fabsf(s) > 1000.0f) ? 0.0f : s;
        float v = fk[p] + bp * INV_DINV;
        if (doClamp) v = fmaxf(v, EPS_F);
        fk[p] = v;
        // quad-image updates: pixel (py,px) lives in 2 elements per layout
        Qf[((py + 1) * QW + (px + 1)) * 2]      = v;
        Qf[(py * QW + (px + 1)) * 2 + 1]        = v;
        QTf[((px + 1) * QW + (py + 1)) * 2]     = v;
        QTf[(px * QW + (py + 1)) * 2 + 1]       = v;
    }
}

// ---------------- select (fused residual reduce) ----------------
__global__ __launch_bounds__(256)
void select_kernel(float* __restrict__ fcur, float* __restrict__ fk,
                   float* __restrict__ Qf, float* __restrict__ QTf,
                   const float* __restrict__ part) {
    __shared__ float buf[4];
    const int tid = threadIdx.x;
    float a = part[tid] + part[tid + 256] + part[tid + 512] + part[tid + 768];
    #pragma unroll
    for (int off = 32; off; off >>= 1) a += __shfl_down(a, off);
    if ((tid & 63) == 0) buf[tid >> 6] = a;
    __syncthreads();
    float tot = buf[0] + buf[1] + buf[2] + buf[3];
    bool upd = (tot > RES2_THRESH);     // res = sqrt(res2) > 0.01
    int p = blockIdx.x * 256 + tid;
    int px = p & (NUMPIX - 1), py = p >> 8;
    float v = upd ? fk[p] : fcur[p];
    fcur[p] = v;
    fk[p] = v;
    Qf[((py + 1) * QW + (px + 1)) * 2]      = v;
    Qf[(py * QW + (px + 1)) * 2 + 1]        = v;
    QTf[((px + 1) * QW + (py + 1)) * 2]     = v;
    QTf[(px * QW + (py + 1)) * 2 + 1]       = v;
}

extern "C" void kernel_launch(void* const* d_in, const int* in_sizes, int n_in,
                              void* d_out, int out_size, void* d_ws, size_t ws_size,
                              hipStream_t stream) {
    const float* f0 = (const float*)d_in[0];     // [256,256]
    const float* sino = (const float*)d_in[1];   // [360,367]
    float* fcur = (float*)d_out;                 // [256,256] output "f"
    float* ws = (float*)d_ws;

    float* cosA = ws + OFF_COS;
    float* sinA = ws + OFF_SIN;
    float* minv = ws + OFF_MINV;   // [360,367] indexed by global angle
    float* fk   = ws + OFF_FK;     // [256,256]
    float* Qf   = ws + OFF_Q;      // quad image (normal)
    float* QTf  = ws + OFF_QT;     // quad image (transposed)
    float* diff = ws + OFF_DIFF;   // [90,367]; reused as residual partials

    init_kernel<<<(QN2 + 255) / 256, 256, 0, stream>>>(
        cosA, sinA, Qf, QTf, fk, fcur, f0);

    minv_kernel<<<NRAYS_ALL / 4, 256, 0, stream>>>(minv, cosA, sinA);

    for (int iter = 0; iter < 2; iter++) {
        for (int j = 0; j < NS; j++) {
            fp_kernel<1><<<(NRAYS_SUB + 3) / 4, 256, 0, stream>>>(
                Qf, QTf, sino, minv, diff, cosA, sinA, j, NS, NRAYS_SUB);
            bp_update_kernel<<<NPIX2 / 64, 256, 0, stream>>>(
                fk, Qf, QTf, diff, cosA, sinA, j, (j == NS - 1) ? 1 : 0);
        }
        // residual: grid-stride partials into diff (idle here), then fused
        // reduce inside select_kernel
        fp_kernel<2><<<RES_BLOCKS, 256, 0, stream>>>(
            Qf, QTf, sino, nullptr, diff, cosA, sinA, 0, 1, NRAYS_ALL);
        select_kernel<<<NPIX2 / 256, 256, 0, stream>>>(fcur, fk, Qf, QTf, diff);
    }
}

// Round 7
// 390.757 us; speedup vs baseline: 1.0697x; 1.0697x over previous
//
#include <hip/hip_runtime.h>
#include <math.h>

#define NUMPIX 256
#define NUMBIN 367
#define NUMTHETA 360
#define NS 4
#define NT 367
#define NPIX2 (NUMPIX * NUMPIX)          // 65536
#define NRAYS_ALL (NUMTHETA * NUMBIN)    // 132120
#define NANG_SUB (NUMTHETA / NS)         // 90
#define NRAYS_SUB (NANG_SUB * NUMBIN)    // 33030

#define CDET 183.0f
#define CPIX 127.5f
#define TOFF 183.0f                      // (NT-1)/2
#define DEN_EPS 1e-6f
#define EPS_F 2.2204460492503131e-16f    // float64 eps
#define RES2_THRESH 1e-4f                // (0.01)^2
#define INV_DINV (1.0f / 90.0f)          // backproject(ones) == 90 exactly

// quad-interleaved image: element (r,c) = float2(img[r][c], img[r+1][c])
// rows r in [-1,256] stored at +1 (258 rows), cols c in [-1,258] at +1
#define QW 260                           // float2 stride
#define QROWS 258
#define QN2 (QW * QROWS)                 // 67080 float2
#define QNF (QN2 * 2)                    // 134160 floats

#define RES_BLOCKS 4096                  // MODE-2 grid (grid-stride)

typedef float f4q __attribute__((ext_vector_type(4), aligned(8)));
typedef float f2u __attribute__((ext_vector_type(2), aligned(4)));

// ---- workspace layout (in floats) ----
#define OFF_COS   0
#define OFF_SIN   (OFF_COS + NUMTHETA)           // 360
#define OFF_MINV  (OFF_SIN + NUMTHETA)           // 720
#define OFF_FK    (OFF_MINV + NRAYS_ALL)         // 132840
#define OFF_Q     (OFF_FK + NPIX2)               // 198376 (even -> float2 ok)
#define OFF_QT    (OFF_Q + QNF)                  // 332536
#define OFF_DIFF  (OFF_QT + QNF)                 // 466696 (also residual partials)

// generic t-interval clip: keep c0 + rate*tt within (bLo, bHi)
__device__ __forceinline__ void clip_axis2(float c0, float rate,
                                           float bLo, float bHi,
                                           float& lo, float& hi) {
    if (fabsf(rate) > 1e-6f) {
        float inv = 1.0f / rate;
        float a = (bLo - c0) * inv;
        float b = (bHi - c0) * inv;
        lo = fmaxf(lo, fminf(a, b));
        hi = fminf(hi, fmaxf(a, b));
    } else if (c0 <= bLo || c0 >= bHi) {
        lo = 1e9f; hi = -1e9f;
    }
}

__device__ __forceinline__ int ray_chunks(float x0, float y0, float ca, float sa,
                                          int& itlo) {
    float lo = -1e9f, hi = 1e9f;
    clip_axis2(x0, -sa, -2.0f, 257.0f, lo, hi);
    clip_axis2(y0,  ca, -2.0f, 257.0f, lo, hi);
    if (hi < lo) { itlo = 0; return 0; }
    int a = (int)floorf(lo + TOFF) - 1; if (a < 0) a = 0;
    int b = (int)ceilf(hi + TOFF) + 1;  if (b > NT - 1) b = NT - 1;
    itlo = a;
    if (b < a) return 0;
    return (b - a + 64) >> 6;
}

// ---------------- init: trig + fk/fcur + quad images ----------------
__global__ void init_kernel(float* __restrict__ cosA, float* __restrict__ sinA,
                            float* __restrict__ Qf, float* __restrict__ QTf,
                            float* __restrict__ fk, float* __restrict__ fcur,
                            const float* __restrict__ f0) {
    int idx = blockIdx.x * blockDim.x + threadIdx.x;
    if (idx < NUMTHETA) {
        float th = (float)((double)idx * 0.017453292519943295);
        cosA[idx] = (float)cos((double)th);
        sinA[idx] = (float)sin((double)th);
    }
    if (idx < NPIX2) {
        float v = f0[idx];
        fk[idx] = v;
        fcur[idx] = v;
    }
    if (idx < QN2) {
        int qr = idx / QW, qc = idx - qr * QW;
        int r = qr - 1, c = qc - 1;                 // r in [-1,256], c in [-1,258]
        bool cv = ((unsigned)c < 256u);
        bool rv0 = ((unsigned)r < 256u), rv1 = ((unsigned)(r + 1) < 256u);
        float a = (cv && rv0) ? f0[r * NUMPIX + c] : 0.0f;
        float b = (cv && rv1) ? f0[(r + 1) * NUMPIX + c] : 0.0f;
        Qf[idx * 2] = a;  Qf[idx * 2 + 1] = b;
        // transposed image: imgT(r,c) = f0[c][r]
        float ta = (cv && rv0) ? f0[c * NUMPIX + r] : 0.0f;
        float tb = (cv && rv1) ? f0[c * NUMPIX + (r + 1)] : 0.0f;
        QTf[idx * 2] = ta;  QTf[idx * 2 + 1] = tb;
    }
}

// ---------------- Minv: analytic interior count + exact edge samples -----
__global__ __launch_bounds__(256)
void minv_kernel(float* __restrict__ minv,
                 const float* __restrict__ cosA,
                 const float* __restrict__ sinA) {
    const int wid = threadIdx.x >> 6, lane = threadIdx.x & 63;
    int ray = blockIdx.x * 4 + wid;               // grid 33030 -> 132120 exact
    int angle = ray / NUMBIN;
    int bin = ray - angle * NUMBIN;
    float ca = cosA[angle], sa = sinA[angle];
    float s = (float)bin - CDET;
    float x0 = fmaf(s, ca, CPIX);                 // x(tt) = x0 - tt*sa
    float y0 = fmaf(s, sa, CPIX);                 // y(tt) = y0 + tt*ca
    float acc = 0.0f;
    int count = 0;
    float lo = -1e9f, hi = 1e9f;
    clip_axis2(x0, -sa, -2.0f, 257.0f, lo, hi);
    clip_axis2(y0,  ca, -2.0f, 257.0f, lo, hi);
    int e1a = 0, e1b = -1, e2a = 0, e2b = -1;
    if (hi >= lo) {
        int itA = (int)floorf(lo + TOFF) - 1; if (itA < 0) itA = 0;
        int itB = (int)ceilf(hi + TOFF) + 1;  if (itB > NT - 1) itB = NT - 1;
        if (itB >= itA) {
            // strict interior: both coords in (0.05, 254.95) -> weight exactly 1
            float ilo = -1e9f, ihi = 1e9f;
            clip_axis2(x0, -sa, 0.05f, 254.95f, ilo, ihi);
            clip_axis2(y0,  ca, 0.05f, 254.95f, ilo, ihi);
            int jA = 1, jB = 0;
            if (ihi >= ilo) {
                jA = (int)ceilf(ilo + TOFF) + 1;
                jB = (int)floorf(ihi + TOFF) - 1;
                if (jA < itA) jA = itA;
                if (jB > itB) jB = itB;
            }
            if (jB >= jA) {
                count = jB - jA + 1;
                e1a = itA; e1b = jA - 1;
                e2a = jB + 1; e2b = itB;
            } else {
                e1a = itA; e1b = itB;       // no interior: one full edge loop
            }
        }
    }
    #pragma unroll 1
    for (int base = e1a; base <= e1b; base += 64) {
        int t = base + lane;
        float tt = (float)t - TOFF;
        float x = fmaf(-tt, sa, x0);
        float y = fmaf(tt, ca, y0);
        float fx = floorf(x), fy = floorf(y);
        float wx = x - fx, wy = y - fy;
        int c0 = (int)fx, r0 = (int)fy;
        float ux = (((unsigned)c0 < 256u) ? (1.0f - wx) : 0.0f) +
                   (((unsigned)(c0 + 1) < 256u) ? wx : 0.0f);
        float uy = (((unsigned)r0 < 256u) ? (1.0f - wy) : 0.0f) +
                   (((unsigned)(r0 + 1) < 256u) ? wy : 0.0f);
        if (t <= e1b) acc += ux * uy;
    }
    #pragma unroll 1
    for (int base = e2a; base <= e2b; base += 64) {
        int t = base + lane;
        float tt = (float)t - TOFF;
        float x = fmaf(-tt, sa, x0);
        float y = fmaf(tt, ca, y0);
        float fx = floorf(x), fy = floorf(y);
        float wx = x - fx, wy = y - fy;
        int c0 = (int)fx, r0 = (int)fy;
        float ux = (((unsigned)c0 < 256u) ? (1.0f - wx) : 0.0f) +
                   (((unsigned)(c0 + 1) < 256u) ? wx : 0.0f);
        float uy = (((unsigned)r0 < 256u) ? (1.0f - wy) : 0.0f) +
                   (((unsigned)(r0 + 1) < 256u) ? wy : 0.0f);
        if (t <= e2b) acc += ux * uy;
    }
    #pragma unroll
    for (int off = 32; off; off >>= 1) acc += __shfl_down(acc, off);
    if (lane == 0) minv[ray] = fmaxf(acc + (float)count, DEN_EPS);
}

// ---------------- forward projection (quad layout: 1 load = 4 corners) ---
// MODE 1: one ray/wave; diffs[ray] = (sino - FP) / Minv
// MODE 2: grid-stride; out[blockIdx.x] = block partial of sum((FP - sino)^2)
template <int MODE>
__global__ __launch_bounds__(256)
void fp_kernel(const float* __restrict__ Qn,
               const float* __restrict__ Qt,
               const float* __restrict__ sino,
               const float* __restrict__ minv,
               float* __restrict__ out,
               const float* __restrict__ cosA,
               const float* __restrict__ sinA,
               int angleStart, int angleStride, int nRays) {
    const int wid = threadIdx.x >> 6, lane = threadIdx.x & 63;
    float wacc = 0.0f;

    int ray = blockIdx.x * 4 + wid;
    if (MODE == 1 && ray >= nRays) return;
    const int rayStep = RES_BLOCKS * 4;

    for (; ray < nRays; ray += rayStep) {
        int ai = ray / NUMBIN;
        int bin = ray - ai * NUMBIN;
        int angle = angleStart + ai * angleStride;
        float ca = cosA[angle], sa = sinA[angle];
        float s = (float)bin - CDET;
        float x0 = fmaf(s, ca, CPIX);             // x(tt) = x0 - tt*sa
        float y0 = fmaf(s, sa, CPIX);             // y(tt) = y0 + tt*ca
        int itlo, nc = ray_chunks(x0, y0, ca, sa, itlo);

        bool useT = fabsf(ca) > fabsf(sa);        // wave-uniform
        const float* img = (useT ? Qt : Qn) + (QW + 1) * 2;  // origin (r=0,c=0)
        float u0 = useT ? y0 : x0, du = useT ? ca : -sa;   // fast (contiguous)
        float v0 = useT ? x0 : y0, dv = useT ? -sa : ca;   // slow (strided)

        float tt0 = (float)(itlo + lane) - TOFF;
        float u = fmaf(tt0, du, u0);
        float v = fmaf(tt0, dv, v0);
        const float du64 = du * 64.0f, dv64 = dv * 64.0f;

        float acc = 0.0f;
        for (int ic = 0; ic < nc; ic++) {
            float uc = fminf(fmaxf(u, -1.0f), 256.0f);   // into zero guard band
            float vc = fminf(fmaxf(v, -1.0f), 256.0f);
            float fu = floorf(uc), fv = floorf(vc);
            float wu = uc - fu, wv = vc - fv;
            int cu = (int)fu, rv = (int)fv;
            const float* p = img + (rv * QW + cu) * 2;
            f4q q = *(const f4q*)p;   // (v00, v10, v01, v11) in one 16B load
            float top = fmaf(wu, q.z - q.x, q.x);
            float bot = fmaf(wu, q.w - q.y, q.y);
            acc += fmaf(wv, bot - top, top);
            u += du64; v += dv64;
        }
        #pragma unroll
        for (int off = 32; off; off >>= 1) acc += __shfl_down(acc, off);
        if (lane == 0) {
            if (MODE == 1) {
                out[ray] = (sino[angle * NUMBIN + bin] - acc) /
                           minv[angle * NUMBIN + bin];
            } else {
                float d = acc - sino[angle * NUMBIN + bin];
                wacc += d * d;
            }
        }
        if (MODE == 1) break;
    }
    if (MODE == 2) {
        __shared__ float part[4];
        if (lane == 0) part[wid] = wacc;
        __syncthreads();
        if (threadIdx.x == 0)
            out[blockIdx.x] = part[0] + part[1] + part[2] + part[3];
    }
}

// ---------------- backprojection + SART update ----------------
__global__ __launch_bounds__(256)
void bp_update_kernel(float* __restrict__ fk,
                      float* __restrict__ Qf,
                      float* __restrict__ QTf,
                      const float* __restrict__ g,      // diffs [90,367]
                      const float* __restrict__ cosA,
                      const float* __restrict__ sinA,
                      int j, int doClamp) {
    __shared__ float part[4][64];
    const int tx = threadIdx.x & 63;
    const int ty = threadIdx.x >> 6;
    int p = blockIdx.x * 64 + tx;
    int px = p & (NUMPIX - 1), py = p >> 8;
    float X = (float)px - CPIX, Y = (float)py - CPIX;
    float acc = 0.0f;
    for (int i = ty; i < NANG_SUB; i += 4) {
        int angle = j + NS * i;
        float ca = cosA[angle], sa = sinA[angle];
        float sd = fmaf(X, ca, fmaf(Y, sa, CDET));   // always in [2.7, 363.3]
        float f0 = floorf(sd);
        float w = sd - f0;
        int i0 = (int)f0;
        f2u gv = *(const f2u*)(g + i * NUMBIN + i0);
        acc += fmaf(w, gv.y - gv.x, gv.x);
    }
    part[ty][tx] = acc;
    __syncthreads();
    if (ty == 0) {
        float s = part[0][tx] + part[1][tx] + part[2][tx] + part[3][tx];
        float bp = (fabsf(s) > 1000.0f) ? 0.0f : s;
        float v = fk[p] + bp * INV_DINV;
        if (doClamp) v = fmaxf(v, EPS_F);
        fk[p] = v;
        // quad-image updates: pixel (py,px) lives in 2 elements per layout
        Qf[((py + 1) * QW + (px + 1)) * 2]      = v;
        Qf[(py * QW + (px + 1)) * 2 + 1]        = v;
        QTf[((px + 1) * QW + (py + 1)) * 2]     = v;
        QTf[(px * QW + (py + 1)) * 2 + 1]       = v;
    }
}

// ---------------- select (fused residual reduce over 4096 partials) ------
__global__ __launch_bounds__(256)
void select_kernel(float* __restrict__ fcur, float* __restrict__ fk,
                   float* __restrict__ Qf, float* __restrict__ QTf,
                   const float* __restrict__ part) {
    __shared__ float buf[4];
    const int tid = threadIdx.x;
    float a = 0.0f;
    #pragma unroll
    for (int k = 0; k < RES_BLOCKS / 256; k++) a += part[tid + k * 256];
    #pragma unroll
    for (int off = 32; off; off >>= 1) a += __shfl_down(a, off);
    if ((tid & 63) == 0) buf[tid >> 6] = a;
    __syncthreads();
    float tot = buf[0] + buf[1] + buf[2] + buf[3];
    bool upd = (tot > RES2_THRESH);     // res = sqrt(res2) > 0.01
    int p = blockIdx.x * 256 + tid;
    int px = p & (NUMPIX - 1), py = p >> 8;
    float v = upd ? fk[p] : fcur[p];
    fcur[p] = v;
    fk[p] = v;
    Qf[((py + 1) * QW + (px + 1)) * 2]      = v;
    Qf[(py * QW + (px + 1)) * 2 + 1]        = v;
    QTf[((px + 1) * QW + (py + 1)) * 2]     = v;
    QTf[(px * QW + (py + 1)) * 2 + 1]       = v;
}

extern "C" void kernel_launch(void* const* d_in, const int* in_sizes, int n_in,
                              void* d_out, int out_size, void* d_ws, size_t ws_size,
                              hipStream_t stream) {
    const float* f0 = (const float*)d_in[0];     // [256,256]
    const float* sino = (const float*)d_in[1];   // [360,367]
    float* fcur = (float*)d_out;                 // [256,256] output "f"
    float* ws = (float*)d_ws;

    float* cosA = ws + OFF_COS;
    float* sinA = ws + OFF_SIN;
    float* minv = ws + OFF_MINV;   // [360,367] indexed by global angle
    float* fk   = ws + OFF_FK;     // [256,256]
    float* Qf   = ws + OFF_Q;      // quad image (normal)
    float* QTf  = ws + OFF_QT;     // quad image (transposed)
    float* diff = ws + OFF_DIFF;   // [90,367]; reused as residual partials

    init_kernel<<<(QN2 + 255) / 256, 256, 0, stream>>>(
        cosA, sinA, Qf, QTf, fk, fcur, f0);

    minv_kernel<<<NRAYS_ALL / 4, 256, 0, stream>>>(minv, cosA, sinA);

    for (int iter = 0; iter < 2; iter++) {
        for (int j = 0; j < NS; j++) {
            fp_kernel<1><<<(NRAYS_SUB + 3) / 4, 256, 0, stream>>>(
                Qf, QTf, sino, minv, diff, cosA, sinA, j, NS, NRAYS_SUB);
            bp_update_kernel<<<NPIX2 / 64, 256, 0, stream>>>(
                fk, Qf, QTf, diff, cosA, sinA, j, (j == NS - 1) ? 1 : 0);
        }
        // residual: grid-stride partials into diff (idle here), then fused
        // reduce inside select_kernel
        fp_kernel<2><<<RES_BLOCKS, 256, 0, stream>>>(
            Qf, QTf, sino, nullptr, diff, cosA, sinA, 0, 1, NRAYS_ALL);
        select_kernel<<<NPIX2 / 256, 256, 0, stream>>>(fcur, fk, Qf, QTf, diff);
    }
}

// Round 9
// 388.145 us; speedup vs baseline: 1.0769x; 1.0067x over previous
//
#include <hip/hip_runtime.h>
#include <math.h>

#define NUMPIX 256
#define NUMBIN 367
#define NUMTHETA 360
#define NS 4
#define NT 367
#define NPIX2 (NUMPIX * NUMPIX)          // 65536
#define NRAYS_ALL (NUMTHETA * NUMBIN)    // 132120
#define NANG_SUB (NUMTHETA / NS)         // 90
#define NRAYS_SUB (NANG_SUB * NUMBIN)    // 33030

#define CDET 183.0f
#define CPIX 127.5f
#define TOFF 183.0f                      // (NT-1)/2
#define DEN_EPS 1e-6f
#define EPS_F 2.2204460492503131e-16f    // float64 eps
#define RES2_THRESH 1e-4f                // (0.01)^2
#define INV_DINV (1.0f / 90.0f)          // backproject(ones) == 90 exactly

// quad-interleaved image: element (r,c) = float2(img[r][c], img[r+1][c])
// rows r in [-1,256] stored at +1 (258 rows), cols c in [-1,258] at +1
// NOTE: sampling clamps coords to [-1,256]; the clamp is the TAIL MASK for
// the up-to-63 overshoot lanes of the rounded-up chunk loop (clamped samples
// read a zero pad cell with weight 0 on the interior side -> contribute 0).
// Do NOT remove it (round-8 failure).
#define QW 260                           // float2 stride
#define QROWS 258
#define QN2 (QW * QROWS)                 // 67080 float2
#define QNF (QN2 * 2)                    // 134160 floats

#define RES_BLOCKS 4096                  // MODE-2 grid (grid-stride)

typedef float f4q __attribute__((ext_vector_type(4), aligned(8)));
typedef float f2u __attribute__((ext_vector_type(2), aligned(4)));

// ---- workspace layout (in floats) ----
#define OFF_COS   0
#define OFF_SIN   (OFF_COS + NUMTHETA)           // 360
#define OFF_MINV  (OFF_SIN + NUMTHETA)           // 720
#define OFF_FK    (OFF_MINV + NRAYS_ALL)         // 132840
#define OFF_Q     (OFF_FK + NPIX2)               // 198376 (even -> float2 ok)
#define OFF_QT    (OFF_Q + QNF)                  // 332536
#define OFF_DIFF  (OFF_QT + QNF)                 // 466696 (also residual partials)

// generic t-interval clip: keep c0 + rate*tt within (bLo, bHi)
__device__ __forceinline__ void clip_axis2(float c0, float rate,
                                           float bLo, float bHi,
                                           float& lo, float& hi) {
    if (fabsf(rate) > 1e-6f) {
        float inv = 1.0f / rate;
        float a = (bLo - c0) * inv;
        float b = (bHi - c0) * inv;
        lo = fmaxf(lo, fminf(a, b));
        hi = fminf(hi, fmaxf(a, b));
    } else if (c0 <= bLo || c0 >= bHi) {
        lo = 1e9f; hi = -1e9f;
    }
}

__device__ __forceinline__ int ray_chunks(float x0, float y0, float ca, float sa,
                                          int& itlo) {
    float lo = -1e9f, hi = 1e9f;
    clip_axis2(x0, -sa, -2.0f, 257.0f, lo, hi);
    clip_axis2(y0,  ca, -2.0f, 257.0f, lo, hi);
    if (hi < lo) { itlo = 0; return 0; }
    int a = (int)floorf(lo + TOFF) - 1; if (a < 0) a = 0;
    int b = (int)ceilf(hi + TOFF) + 1;  if (b > NT - 1) b = NT - 1;
    itlo = a;
    if (b < a) return 0;
    return (b - a + 64) >> 6;
}

// ---------------- init: trig + fk/fcur + quad images ----------------
__global__ void init_kernel(float* __restrict__ cosA, float* __restrict__ sinA,
                            float* __restrict__ Qf, float* __restrict__ QTf,
                            float* __restrict__ fk, float* __restrict__ fcur,
                            const float* __restrict__ f0) {
    int idx = blockIdx.x * blockDim.x + threadIdx.x;
    if (idx < NUMTHETA) {
        float th = (float)((double)idx * 0.017453292519943295);
        cosA[idx] = (float)cos((double)th);
        sinA[idx] = (float)sin((double)th);
    }
    if (idx < NPIX2) {
        float v = f0[idx];
        fk[idx] = v;
        fcur[idx] = v;
    }
    if (idx < QN2) {
        int qr = idx / QW, qc = idx - qr * QW;
        int r = qr - 1, c = qc - 1;                 // r in [-1,256], c in [-1,258]
        bool cv = ((unsigned)c < 256u);
        bool rv0 = ((unsigned)r < 256u), rv1 = ((unsigned)(r + 1) < 256u);
        float a = (cv && rv0) ? f0[r * NUMPIX + c] : 0.0f;
        float b = (cv && rv1) ? f0[(r + 1) * NUMPIX + c] : 0.0f;
        Qf[idx * 2] = a;  Qf[idx * 2 + 1] = b;
        // transposed image: imgT(r,c) = f0[c][r]
        float ta = (cv && rv0) ? f0[c * NUMPIX + r] : 0.0f;
        float tb = (cv && rv1) ? f0[c * NUMPIX + (r + 1)] : 0.0f;
        QTf[idx * 2] = ta;  QTf[idx * 2 + 1] = tb;
    }
}

// ---------------- Minv: analytic interior count + exact edge samples -----
__global__ __launch_bounds__(256)
void minv_kernel(float* __restrict__ minv,
                 const float* __restrict__ cosA,
                 const float* __restrict__ sinA) {
    const int wid = threadIdx.x >> 6, lane = threadIdx.x & 63;
    int ray = blockIdx.x * 4 + wid;               // grid 33030 -> 132120 exact
    int angle = ray / NUMBIN;
    int bin = ray - angle * NUMBIN;
    float ca = cosA[angle], sa = sinA[angle];
    float s = (float)bin - CDET;
    float x0 = fmaf(s, ca, CPIX);                 // x(tt) = x0 - tt*sa
    float y0 = fmaf(s, sa, CPIX);                 // y(tt) = y0 + tt*ca
    float acc = 0.0f;
    int count = 0;
    float lo = -1e9f, hi = 1e9f;
    clip_axis2(x0, -sa, -2.0f, 257.0f, lo, hi);
    clip_axis2(y0,  ca, -2.0f, 257.0f, lo, hi);
    int e1a = 0, e1b = -1, e2a = 0, e2b = -1;
    if (hi >= lo) {
        int itA = (int)floorf(lo + TOFF) - 1; if (itA < 0) itA = 0;
        int itB = (int)ceilf(hi + TOFF) + 1;  if (itB > NT - 1) itB = NT - 1;
        if (itB >= itA) {
            // strict interior: both coords in (0.05, 254.95) -> weight exactly 1
            float ilo = -1e9f, ihi = 1e9f;
            clip_axis2(x0, -sa, 0.05f, 254.95f, ilo, ihi);
            clip_axis2(y0,  ca, 0.05f, 254.95f, ilo, ihi);
            int jA = 1, jB = 0;
            if (ihi >= ilo) {
                jA = (int)ceilf(ilo + TOFF) + 1;
                jB = (int)floorf(ihi + TOFF) - 1;
                if (jA < itA) jA = itA;
                if (jB > itB) jB = itB;
            }
            if (jB >= jA) {
                count = jB - jA + 1;
                e1a = itA; e1b = jA - 1;
                e2a = jB + 1; e2b = itB;
            } else {
                e1a = itA; e1b = itB;       // no interior: one full edge loop
            }
        }
    }
    #pragma unroll 1
    for (int base = e1a; base <= e1b; base += 64) {
        int t = base + lane;
        float tt = (float)t - TOFF;
        float x = fmaf(-tt, sa, x0);
        float y = fmaf(tt, ca, y0);
        float fx = floorf(x), fy = floorf(y);
        float wx = x - fx, wy = y - fy;
        int c0 = (int)fx, r0 = (int)fy;
        float ux = (((unsigned)c0 < 256u) ? (1.0f - wx) : 0.0f) +
                   (((unsigned)(c0 + 1) < 256u) ? wx : 0.0f);
        float uy = (((unsigned)r0 < 256u) ? (1.0f - wy) : 0.0f) +
                   (((unsigned)(r0 + 1) < 256u) ? wy : 0.0f);
        if (t <= e1b) acc += ux * uy;
    }
    #pragma unroll 1
    for (int base = e2a; base <= e2b; base += 64) {
        int t = base + lane;
        float tt = (float)t - TOFF;
        float x = fmaf(-tt, sa, x0);
        float y = fmaf(tt, ca, y0);
        float fx = floorf(x), fy = floorf(y);
        float wx = x - fx, wy = y - fy;
        int c0 = (int)fx, r0 = (int)fy;
        float ux = (((unsigned)c0 < 256u) ? (1.0f - wx) : 0.0f) +
                   (((unsigned)(c0 + 1) < 256u) ? wx : 0.0f);
        float uy = (((unsigned)r0 < 256u) ? (1.0f - wy) : 0.0f) +
                   (((unsigned)(r0 + 1) < 256u) ? wy : 0.0f);
        if (t <= e2b) acc += ux * uy;
    }
    #pragma unroll
    for (int off = 32; off; off >>= 1) acc += __shfl_down(acc, off);
    if (lane == 0) minv[ray] = fmaxf(acc + (float)count, DEN_EPS);
}

// ---------------- forward projection (quad layout: 1 load = 4 corners) ---
// MODE 1: one ray/wave; diffs[ray] = (sino - FP) / Minv
// MODE 2: grid-stride; out[blockIdx.x] = block partial of sum((FP - sino)^2)
template <int MODE>
__global__ __launch_bounds__(256)
void fp_kernel(const float* __restrict__ Qn,
               const float* __restrict__ Qt,
               const float* __restrict__ sino,
               const float* __restrict__ minv,
               float* __restrict__ out,
               const float* __restrict__ cosA,
               const float* __restrict__ sinA,
               int angleStart, int angleStride, int nRays) {
    const int wid = threadIdx.x >> 6, lane = threadIdx.x & 63;
    float wacc = 0.0f;

    int ray = blockIdx.x * 4 + wid;
    if (MODE == 1 && ray >= nRays) return;
    const int rayStep = RES_BLOCKS * 4;

    for (; ray < nRays; ray += rayStep) {
        int ai = ray / NUMBIN;
        int bin = ray - ai * NUMBIN;
        int angle = angleStart + ai * angleStride;
        float ca = cosA[angle], sa = sinA[angle];
        float s = (float)bin - CDET;
        float x0 = fmaf(s, ca, CPIX);             // x(tt) = x0 - tt*sa
        float y0 = fmaf(s, sa, CPIX);             // y(tt) = y0 + tt*ca
        int itlo, nc = ray_chunks(x0, y0, ca, sa, itlo);

        bool useT = fabsf(ca) > fabsf(sa);        // wave-uniform
        const float* img = (useT ? Qt : Qn) + (QW + 1) * 2;  // origin (r=0,c=0)
        float u0 = useT ? y0 : x0, du = useT ? ca : -sa;   // fast (contiguous)
        float v0 = useT ? x0 : y0, dv = useT ? -sa : ca;   // slow (strided)

        float tt0 = (float)(itlo + lane) - TOFF;
        float u = fmaf(tt0, du, u0);
        float v = fmaf(tt0, dv, v0);
        const float du64 = du * 64.0f, dv64 = dv * 64.0f;

        float acc = 0.0f;
        for (int ic = 0; ic < nc; ic++) {
            float uc = fminf(fmaxf(u, -1.0f), 256.0f);   // tail mask + guard
            float vc = fminf(fmaxf(v, -1.0f), 256.0f);
            float fu = floorf(uc), fv = floorf(vc);
            float wu = uc - fu, wv = vc - fv;
            // exact integer fp32 index: fv*260+fu in [-261, 66816] < 2^23
            int idx = (int)fmaf(fv, (float)QW, fu);
            const float* p = img + idx * 2;
            f4q q = *(const f4q*)p;   // (v00, v10, v01, v11) in one 16B load
            float top = fmaf(wu, q.z - q.x, q.x);
            float bot = fmaf(wu, q.w - q.y, q.y);
            acc += fmaf(wv, bot - top, top);
            u += du64; v += dv64;
        }
        #pragma unroll
        for (int off = 32; off; off >>= 1) acc += __shfl_down(acc, off);
        if (lane == 0) {
            if (MODE == 1) {
                out[ray] = (sino[angle * NUMBIN + bin] - acc) /
                           minv[angle * NUMBIN + bin];
            } else {
                float d = acc - sino[angle * NUMBIN + bin];
                wacc += d * d;
            }
        }
        if (MODE == 1) break;
    }
    if (MODE == 2) {
        __shared__ float part[4];
        if (lane == 0) part[wid] = wacc;
        __syncthreads();
        if (threadIdx.x == 0)
            out[blockIdx.x] = part[0] + part[1] + part[2] + part[3];
    }
}

// ---------------- backprojection + SART update ----------------
__global__ __launch_bounds__(256)
void bp_update_kernel(float* __restrict__ fk,
                      float* __restrict__ Qf,
                      float* __restrict__ QTf,
                      const float* __restrict__ g,      // diffs [90,367]
                      const float* __restrict__ cosA,
                      const float* __restrict__ sinA,
                      int j, int doClamp) {
    __shared__ float part[4][64];
    const int tx = threadIdx.x & 63;
    const int ty = threadIdx.x >> 6;
    int p = blockIdx.x * 64 + tx;
    int px = p & (NUMPIX - 1), py = p >> 8;
    float X = (float)px - CPIX, Y = (float)py - CPIX;
    float acc = 0.0f;
    for (int i = ty; i < NANG_SUB; i += 4) {
        int angle = j + NS * i;
        float ca = cosA[angle], sa = sinA[angle];
        float sd = fmaf(X, ca, fmaf(Y, sa, CDET));   // always in [2.7, 363.3]
        float f0 = floorf(sd);
        float w = sd - f0;
        int i0 = (int)f0;
        f2u gv = *(const f2u*)(g + i * NUMBIN + i0);
        acc += fmaf(w, gv.y - gv.x, gv.x);
    }
    part[ty][tx] = acc;
    __syncthreads();
    if (ty == 0) {
        float s = part[0][tx] + part[1][tx] + part[2][tx] + part[3][tx];
        float bp = (fabsf(s) > 1000.0f) ? 0.0f : s;
        float v = fk[p] + bp * INV_DINV;
        if (doClamp) v = fmaxf(v, EPS_F);
        fk[p] = v;
        // quad-image updates: pixel (py,px) lives in 2 elements per layout
        Qf[((py + 1) * QW + (px + 1)) * 2]      = v;
        Qf[(py * QW + (px + 1)) * 2 + 1]        = v;
        QTf[((px + 1) * QW + (py + 1)) * 2]     = v;
        QTf[(px * QW + (py + 1)) * 2 + 1]       = v;
    }
}

// ---------------- select (fused residual reduce over 4096 partials) ------
__global__ __launch_bounds__(256)
void select_kernel(float* __restrict__ fcur, float* __restrict__ fk,
                   float* __restrict__ Qf, float* __restrict__ QTf,
                   const float* __restrict__ part) {
    __shared__ float buf[4];
    const int tid = threadIdx.x;
    float a = 0.0f;
    #pragma unroll
    for (int k = 0; k < RES_BLOCKS / 256; k++) a += part[tid + k * 256];
    #pragma unroll
    for (int off = 32; off; off >>= 1) a += __shfl_down(a, off);
    if ((tid & 63) == 0) buf[tid >> 6] = a;
    __syncthreads();
    float tot = buf[0] + buf[1] + buf[2] + buf[3];
    bool upd = (tot > RES2_THRESH);     // res = sqrt(res2) > 0.01
    int p = blockIdx.x * 256 + tid;
    int px = p & (NUMPIX - 1), py = p >> 8;
    float v = upd ? fk[p] : fcur[p];
    fcur[p] = v;
    fk[p] = v;
    Qf[((py + 1) * QW + (px + 1)) * 2]      = v;
    Qf[(py * QW + (px + 1)) * 2 + 1]        = v;
    QTf[((px + 1) * QW + (py + 1)) * 2]     = v;
    QTf[(px * QW + (py + 1)) * 2 + 1]       = v;
}

extern "C" void kernel_launch(void* const* d_in, const int* in_sizes, int n_in,
                              void* d_out, int out_size, void* d_ws, size_t ws_size,
                              hipStream_t stream) {
    const float* f0 = (const float*)d_in[0];     // [256,256]
    const float* sino = (const float*)d_in[1];   // [360,367]
    float* fcur = (float*)d_out;                 // [256,256] output "f"
    float* ws = (float*)d_ws;

    float* cosA = ws + OFF_COS;
    float* sinA = ws + OFF_SIN;
    float* minv = ws + OFF_MINV;   // [360,367] indexed by global angle
    float* fk   = ws + OFF_FK;     // [256,256]
    float* Qf   = ws + OFF_Q;      // quad image (normal)
    float* QTf  = ws + OFF_QT;     // quad image (transposed)
    float* diff = ws + OFF_DIFF;   // [90,367]; reused as residual partials

    init_kernel<<<(QN2 + 255) / 256, 256, 0, stream>>>(
        cosA, sinA, Qf, QTf, fk, fcur, f0);

    minv_kernel<<<NRAYS_ALL / 4, 256, 0, stream>>>(minv, cosA, sinA);

    for (int iter = 0; iter < 2; iter++) {
        for (int j = 0; j < NS; j++) {
            fp_kernel<1><<<(NRAYS_SUB + 3) / 4, 256, 0, stream>>>(
                Qf, QTf, sino, minv, diff, cosA, sinA, j, NS, NRAYS_SUB);
            bp_update_kernel<<<NPIX2 / 64, 256, 0, stream>>>(
                fk, Qf, QTf, diff, cosA, sinA, j, (j == NS - 1) ? 1 : 0);
        }
        // residual: grid-stride partials into diff (idle here), then fused
        // reduce inside select_kernel
        fp_kernel<2><<<RES_BLOCKS, 256, 0, stream>>>(
            Qf, QTf, sino, nullptr, diff, cosA, sinA, 0, 1, NRAYS_ALL);
        select_kernel<<<NPIX2 / 256, 256, 0, stream>>>(fcur, fk, Qf, QTf, diff);
    }
}